// Round 12
// baseline (80.623 us; speedup 1.0000x reference)
//
#include <hip/hip_runtime.h>
#include <stdint.h>

// Problem dims
#define NB   4096   // batch rows (M)
#define KD   2048   // IN + S   (K)
#define ND   4096   // 4*S      (N, reordered: n -> gate=(n>>4)&3, s=(n>>6)*16+(n&15))
#define SD   1024   // state size

// GEMM tile (256x256, 8 waves = 2M x 4N, m201 8-phase schedule)
#define BM   256
#define BN   256
#define BK   64
#define NKT  (KD / BK)   // 32 K-tiles

using f32x4  = __attribute__((ext_vector_type(4))) float;
using bf16x8 = __attribute__((ext_vector_type(8))) short;

typedef const __attribute__((address_space(1))) uint32_t* gas_u32;
typedef __attribute__((address_space(3))) uint32_t* las_u32;

__device__ __forceinline__ unsigned short f2bf(float f) {
    union { float f; uint32_t u; } c; c.f = f;
    uint32_t u = c.u;
    uint32_t r = (u + 0x7fffu + ((u >> 16) & 1u)) >> 16;  // RNE
    return (unsigned short)r;
}

__device__ __forceinline__ void async_load16(const void* gsrc, void* ldst) {
    __builtin_amdgcn_global_load_lds((gas_u32)gsrc, (las_u32)ldst, 16, 0, 0);
}

__device__ __forceinline__ float frcp(float x) { return __builtin_amdgcn_rcpf(x); }
__device__ __forceinline__ float sigm(float x) { return frcp(1.f + __expf(-x)); }
__device__ __forceinline__ float tanh_fast(float x) {
    return 1.f - 2.f * frcp(1.f + __expf(2.f * x));   // inf-safe
}

// ---------------------------------------------------------------------------
// Pack: fp32 -> bf16, X=[input|old_h]; W rows reordered so GEMM column
// n maps to weights row  gate*SD + (n>>6)*16 + (n&15),  gate=(n>>4)&3.
// ---------------------------------------------------------------------------
__global__ void pack_kernel(const float* __restrict__ input,
                            const float* __restrict__ old_h,
                            const float* __restrict__ weights,
                            const float* __restrict__ bias,
                            unsigned short* __restrict__ Xb,
                            unsigned short* __restrict__ Wb,
                            float* __restrict__ biasR) {
    const int XCH = NB * (KD / 4);
    const int WCH = ND * (KD / 4);
    const int BCH = ND / 4;
    const int total = XCH + WCH + BCH;
    for (int c = blockIdx.x * blockDim.x + threadIdx.x; c < total;
         c += gridDim.x * blockDim.x) {
        if (c < XCH) {
            int b  = c >> 9;
            int k  = (c & 511) << 2;
            const float* src = (k < 1024) ? (input + (size_t)b * 1024 + k)
                                          : (old_h + (size_t)b * 1024 + (k - 1024));
            float4 v = *reinterpret_cast<const float4*>(src);
            ushort4 o;
            o.x = f2bf(v.x); o.y = f2bf(v.y); o.z = f2bf(v.z); o.w = f2bf(v.w);
            *reinterpret_cast<ushort4*>(Xb + (size_t)b * KD + k) = o;
        } else if (c < XCH + WCH) {
            int cc = c - XCH;
            int n  = cc >> 9;
            int k  = (cc & 511) << 2;
            int srow = ((n >> 4) & 3) * SD + ((n >> 6) * 16 + (n & 15));
            float4 v = *reinterpret_cast<const float4*>(weights + (size_t)srow * KD + k);
            ushort4 o;
            o.x = f2bf(v.x); o.y = f2bf(v.y); o.z = f2bf(v.z); o.w = f2bf(v.w);
            *reinterpret_cast<ushort4*>(Wb + (size_t)n * KD + k) = o;
        } else {
            int n4 = (c - XCH - WCH) << 2;
            #pragma unroll
            for (int t = 0; t < 4; ++t) {
                int n = n4 + t;
                biasR[n] = bias[((n >> 4) & 3) * SD + ((n >> 6) * 16 + (n & 15))];
            }
        }
    }
}

// ---------------------------------------------------------------------------
// 256x256 GEMM + fused LSTM epilogue — verbatim m201 8-phase schedule.
// Per phase: {ds_reads (12/4/8/0) ; stage 1 half-tile ; [lgkmcnt(8) if 12] ;
//            s_barrier ; lgkmcnt(0) [NO memory clobber — MFMAs float above
//            it per rule 18; real gating = compiler split RAW waits, so each
//            wave starts MFMAs when ITS frags land -> staggered starts ->
//            LDS drain overlaps other waves' MFMA bursts] ;
//            setprio(1) ; 16 MFMA ; setprio(0) ; [vmcnt(4) @P3/P7] ; s_barrier}
// NO sched_barrier(0) anywhere in the loop (R3-R11's pins forced a full
// collective drain per phase = strict LDS||MFMA serialization, 9x measured).
// Buffers: tile parity = buffer (even->buf0). Phases P0-P3 tile T (buf0),
// P4-P7 tile T+1 (buf1). Stage slots: P0/P1: A(T+1)->Abuf1; P2/P3:
// B(T+2)->Bbuf0; P4/P5: A(T+2)->Abuf0; P6/P7: B(T+3)->Bbuf1.
// Legality (stage at phase q top is safe for region last-read at p if
// q >= p+1, since p-reads drain via RAW before p-MFMAs, before bar2(p)):
// A(T) last read P2 -> staged P4 ok; B(T) last read P1 -> staged P2 ok;
// A(T-1) last read P6(prev) -> P0 ok; B(T+1) last read P5 -> P6 ok.
// vmcnt(4) FIFO invariant: entering iter, outstanding=[B(T+1)x4];
// +P0,P1 A(T+1)x4 +P2,P3 B(T+2)x4 = 12 @P3-tail -> drain 8 = B(T+1),A(T+1)
// landed (read P4-P6). Leaves [B(T+2)x4]; +A(T+2)x4 +B(T+3)x4 = 12 @P7-tail
// -> drain 8 = B(T+2),A(T+2) landed (read next P0-P2). Symmetric.
// Prologue: B(0),A(0),B(1) = 12 loads; vmcnt(4) -> tile0 landed, B(1) in
// flight = the invariant. Wrap stages (T=30: B(0),A(0),B(1)) are dead
// writes into regions whose tiles are past their last read -> legal.
// ---------------------------------------------------------------------------
#define SEG(DB, AB, HALF) (((((DB) * 2 + (AB)) * 2) + (HALF)) * 8192)

#define SBAR   __builtin_amdgcn_s_barrier()
#define LGKM8  asm volatile("s_waitcnt lgkmcnt(8)")
#define LGKM0  asm volatile("s_waitcnt lgkmcnt(0)")
#define VMC4   asm volatile("s_waitcnt vmcnt(4)" ::: "memory")
#define PRIO1  __builtin_amdgcn_s_setprio(1)
#define PRIO0  __builtin_amdgcn_s_setprio(0)

__launch_bounds__(512, 2)
__global__ void lstm_gemm(const unsigned short* __restrict__ Xb,
                          const unsigned short* __restrict__ Wb,
                          const float* __restrict__ biasR,
                          const float* __restrict__ old_cell,
                          float* __restrict__ new_h,
                          float* __restrict__ new_cell) {
    __shared__ unsigned short lds[65536];   // 128 KiB

    const int tid  = threadIdx.x;
    const int lane = tid & 63;
    const int wid  = tid >> 6;       // 0..7
    const int wm   = wid >> 2;       // 0..1  (M half owner)
    const int wn   = wid & 3;        // 0..3  (N quarter owner)
    const int l15  = lane & 15;
    const int krow = lane >> 4;      // 0..3

    // XCD-aware bijective swizzle (256 blocks, 8 XCDs)
    const int wg    = blockIdx.x;
    const int swz   = (wg & 7) * 32 + (wg >> 3);
    const int mblk  = swz >> 4;
    const int nblk  = swz & 15;
    const int rbase = mblk * BM;
    const int nbase = nblk * BN;

    // staging per-thread constants: half-tile = 128 rows x 64 cols = 1024 chunks
    const int c0 = tid, c1 = tid + 512;
    const int srow0 = c0 >> 3, sk0 = ((c0 & 7) ^ (srow0 & 7)) * 8;
    const int srow1 = c1 >> 3, sk1 = ((c1 & 7) ^ (srow1 & 7)) * 8;

    f32x4  acc[8][4] = {};
    bf16x8 a[4][2];        // A frags of current quadrant (in-place reload at P2/P6)
    bf16x8 b0[2][2];       // B frags nq=0 (cols 0-31 of wave panel)
    bf16x8 b1[2][2];       // B frags nq=1 (cols 32-63)

#define STAGE(PTR, TB, KT, DB, AB, HALF) do {                                   \
        async_load16((PTR) + (size_t)((TB) + (HALF) * 128 + srow0) * KD +       \
                         (KT) * BK + sk0,                                       \
                     lds + SEG(DB, AB, HALF) + c0 * 8);                         \
        async_load16((PTR) + (size_t)((TB) + (HALF) * 128 + srow1) * KD +       \
                         (KT) * BK + sk1,                                       \
                     lds + SEG(DB, AB, HALF) + c1 * 8);                         \
    } while (0)

#define LOAD_A(DB, MQ) do {                                                     \
        const unsigned short* base_ = lds + SEG(DB, 0, 0) + wm * 8192;          \
        _Pragma("unroll") for (int i_ = 0; i_ < 4; ++i_)                        \
        _Pragma("unroll") for (int kk_ = 0; kk_ < 2; ++kk_) {                   \
            int r_ = (MQ) * 64 + i_ * 16 + l15;                                 \
            int s_ = kk_ * 4 + krow;                                            \
            a[i_][kk_] = *reinterpret_cast<const bf16x8*>(                      \
                base_ + r_ * 64 + ((s_ ^ (r_ & 7)) * 8));                       \
        }                                                                       \
    } while (0)

#define LOAD_B_TO(DST, DB, NQ) do {                                             \
        const unsigned short* base_ = lds + SEG(DB, 1, 0) + (wn >> 1) * 8192;   \
        _Pragma("unroll") for (int j_ = 0; j_ < 2; ++j_)                        \
        _Pragma("unroll") for (int kk_ = 0; kk_ < 2; ++kk_) {                   \
            int r_ = (wn & 1) * 64 + ((NQ) * 2 + j_) * 16 + l15;                \
            int s_ = kk_ * 4 + krow;                                            \
            DST[j_][kk_] = *reinterpret_cast<const bf16x8*>(                    \
                base_ + r_ * 64 + ((s_ ^ (r_ & 7)) * 8));                       \
        }                                                                       \
    } while (0)

#define MMA_Q(MQ, NQH, BB) do {                                                 \
        _Pragma("unroll") for (int i_ = 0; i_ < 4; ++i_)                        \
        _Pragma("unroll") for (int j_ = 0; j_ < 2; ++j_)                        \
        _Pragma("unroll") for (int kk_ = 0; kk_ < 2; ++kk_)                     \
            acc[(MQ) * 4 + i_][(NQH) * 2 + j_] =                                \
                __builtin_amdgcn_mfma_f32_16x16x32_bf16(                        \
                    a[i_][kk_], BB[j_][kk_],                                    \
                    acc[(MQ) * 4 + i_][(NQH) * 2 + j_], 0, 0, 0);               \
    } while (0)

    // ---- prologue: B(0),A(0) -> buf0; B(1) -> buf1; tile0 landed ----
    STAGE(Wb, nbase, 0, 0, 1, 0);
    STAGE(Wb, nbase, 0, 0, 1, 1);
    STAGE(Xb, rbase, 0, 0, 0, 0);
    STAGE(Xb, rbase, 0, 0, 0, 1);
    STAGE(Wb, nbase, 1, 1, 1, 0);
    STAGE(Wb, nbase, 1, 1, 1, 1);
    VMC4;    // 12 outstanding -> drain 8 = tile0 landed; B(1) in flight
    SBAR;

    // ---- main loop: 8 phases / 2 K-tiles (tile parity = buffer) ----
#define KBODY(TT) do {                                                          \
        const int kt1_ = (TT) + 1;                                              \
        const int kt2_ = ((TT) + 2) & (NKT - 1);                                \
        const int kt3_ = ((TT) + 3) & (NKT - 1);                                \
        /* P0: tile T quadrant (0,0) */                                         \
        LOAD_A(0, 0);                                                           \
        LOAD_B_TO(b0, 0, 0);                                                    \
        STAGE(Xb, rbase, kt1_, 1, 0, 0);                                        \
        LGKM8;                                                                  \
        SBAR; LGKM0; PRIO1; MMA_Q(0, 0, b0); PRIO0; SBAR;                       \
        /* P1: quadrant (0,1) */                                                \
        LOAD_B_TO(b1, 0, 1);                                                    \
        STAGE(Xb, rbase, kt1_, 1, 0, 1);                                        \
        SBAR; LGKM0; PRIO1; MMA_Q(0, 1, b1); PRIO0; SBAR;                       \
        /* P2: quadrant (1,0) */                                                \
        LOAD_A(0, 1);                                                           \
        STAGE(Wb, nbase, kt2_, 0, 1, 0);                                        \
        SBAR; LGKM0; PRIO1; MMA_Q(1, 0, b0); PRIO0; SBAR;                       \
        /* P3: quadrant (1,1); vmcnt gate for tile T+1 */                       \
        STAGE(Wb, nbase, kt2_, 0, 1, 1);                                        \
        SBAR; LGKM0; PRIO1; MMA_Q(1, 1, b1); PRIO0; VMC4; SBAR;                 \
        /* P4: tile T+1 quadrant (0,0) */                                       \
        LOAD_A(1, 0);                                                           \
        LOAD_B_TO(b0, 1, 0);                                                    \
        STAGE(Xb, rbase, kt2_, 0, 0, 0);                                        \
        LGKM8;                                                                  \
        SBAR; LGKM0; PRIO1; MMA_Q(0, 0, b0); PRIO0; SBAR;                       \
        /* P5: quadrant (0,1) */                                                \
        LOAD_B_TO(b1, 1, 1);                                                    \
        STAGE(Xb, rbase, kt2_, 0, 0, 1);                                        \
        SBAR; LGKM0; PRIO1; MMA_Q(0, 1, b1); PRIO0; SBAR;                       \
        /* P6: quadrant (1,0) */                                                \
        LOAD_A(1, 1);                                                           \
        STAGE(Wb, nbase, kt3_, 1, 1, 0);                                        \
        SBAR; LGKM0; PRIO1; MMA_Q(1, 0, b0); PRIO0; SBAR;                       \
        /* P7: quadrant (1,1); vmcnt gate for tile T+2 */                       \
        STAGE(Wb, nbase, kt3_, 1, 1, 1);                                        \
        SBAR; LGKM0; PRIO1; MMA_Q(1, 1, b1); PRIO0; VMC4; SBAR;                 \
    } while (0)

    for (int t = 0; t < NKT; t += 2) {
        KBODY(t);
    }

    // ---- fused LSTM epilogue (reg-resident, zero-shuffle) ----
    const int s = (nblk * 4 + wn) * 16 + l15;
    float bg[4];
    #pragma unroll
    for (int jj = 0; jj < 4; ++jj)
        bg[jj] = biasR[nbase + wn * 64 + jj * 16 + l15];

    #pragma unroll
    for (int mi = 0; mi < 8; ++mi) {
        #pragma unroll
        for (int r = 0; r < 4; ++r) {
            const int row = rbase + wm * 128 + mi * 16 + krow * 4 + r;
            float fg = sigm(acc[mi][0][r] + bg[0]);
            float ig = sigm(acc[mi][1][r] + bg[1]);
            float og = sigm(acc[mi][2][r] + bg[2]);
            float gg = tanh_fast(acc[mi][3][r] + bg[3]);
            float oc = old_cell[(size_t)row * SD + s];
            float nc = fmaf(fg, oc, ig * gg);
            float nh = og * tanh_fast(nc);
            new_h[(size_t)row * SD + s]    = nh;
            new_cell[(size_t)row * SD + s] = nc;
        }
    }
}

extern "C" void kernel_launch(void* const* d_in, const int* in_sizes, int n_in,
                              void* d_out, int out_size, void* d_ws, size_t ws_size,
                              hipStream_t stream) {
    const float* input    = (const float*)d_in[0];
    const float* old_h    = (const float*)d_in[1];
    const float* old_cell = (const float*)d_in[2];
    const float* weights  = (const float*)d_in[3];
    const float* bias     = (const float*)d_in[4];

    unsigned short* Xb  = (unsigned short*)d_ws;                             // 16 MiB
    unsigned short* Wb  = (unsigned short*)((char*)d_ws + (size_t)16777216); // 16 MiB
    float*          bR  = (float*)((char*)d_ws + (size_t)33554432);          // 16 KiB

    float* out_h = (float*)d_out;
    float* out_c = out_h + (size_t)NB * SD;

    pack_kernel<<<2048, 256, 0, stream>>>(input, old_h, weights, bias, Xb, Wb, bR);
    lstm_gemm<<<(NB / BM) * (ND / BN), 512, 0, stream>>>(Xb, Wb, bR, old_cell,
                                                         out_h, out_c);
}